// Round 12
// baseline (115.017 us; speedup 1.0000x reference)
//
#include <hip/hip_runtime.h>
#include <math.h>

#define WH     256
#define NDEPTH 8
#define NBATCH 1024
#define NB     8            // batch elements per block (256 blocks, 1/CU)
#define PLANE  (WH * WH)    // 65536

typedef _Float16 h2 __attribute__((ext_vector_type(2)));

// ws layout (fp16): wsh[arr][ho][d][hs][w]
//   arr: 0=M1 1=B1 2=M2 3=B2 ; ho = h>>5 (wave's 32-row block) ; hs = h&31
// Per (arr,ho): 8*32*256 = 65536 halfs = 128 KB, contiguous across depth ->
// each prop wave streams ONE pointer, +1 KB (64 uint4) per 2-row chunk,
// branchless. Pipeline over-reads <=3 chunks (3 KB) past stream end; fp16 ws
// is 4 MiB and ws_size >= 8 MiB (verified R2) -> harmless.
#define HOBLK  (NDEPTH * 32 * WH)   // halfs per (arr,ho) block = 65536

// ---------------------------------------------------------------------------
// Transpose + fp32->fp16 convert. 512 blocks x 256 threads. (~10us)
// bid = arr(2b) | d(3b) | ht(2b) | wt(2b); 64x64 tile via fp32 LDS (pitch 65).
// ---------------------------------------------------------------------------
__global__ __launch_bounds__(256) void transpose_half_k(const float* __restrict__ M1,
                                                        const float* __restrict__ B1,
                                                        const float* __restrict__ M2,
                                                        const float* __restrict__ B2,
                                                        _Float16* __restrict__ wsh) {
    __shared__ float tile[64][65];
    const int bid = blockIdx.x;
    const int arr = bid >> 7;
    const int d   = (bid >> 4) & 7;
    const int ht  = (bid >> 2) & 3;     // h-tile (64 rows)
    const int wt  = bid & 3;            // w-tile

    const float* src = (arr == 0) ? M1 : (arr == 1) ? B1 : (arr == 2) ? M2 : B2;
    const float* s = src + d * PLANE;

    const int t   = threadIdx.x;
    const int q16 = t >> 4;     // 0..15
    const int r16 = t & 15;     // 0..15

#pragma unroll
    for (int p = 0; p < 4; ++p) {        // read: float4 along h ([d][w][h])
        const int wrow = q16 + p * 16;
        const float4 v = *(const float4*)(s + (wt * 64 + wrow) * WH + ht * 64 + r16 * 4);
        tile[wrow][r16 * 4 + 0] = v.x;
        tile[wrow][r16 * 4 + 1] = v.y;
        tile[wrow][r16 * 4 + 2] = v.z;
        tile[wrow][r16 * 4 + 3] = v.w;
    }
    __syncthreads();
#pragma unroll
    for (int p = 0; p < 4; ++p) {        // write: 4 halfs along w
        const int hrow = q16 + p * 16;   // local h 0..63
        const int ho   = ht * 2 + (hrow >> 5);
        const int hs   = hrow & 31;
        const int wl   = r16 * 4;
        _Float16* o = wsh + ((size_t)(arr * 8 + ho) * NDEPTH + d) * (32 * WH)
                          + hs * WH + wt * 64 + wl;
        union { _Float16 f[4]; uint2 u; } pk;
        pk.f[0] = (_Float16)tile[wl + 0][hrow];
        pk.f[1] = (_Float16)tile[wl + 1][hrow];
        pk.f[2] = (_Float16)tile[wl + 2][hrow];
        pk.f[3] = (_Float16)tile[wl + 3][hrow];
        *(uint2*)o = pk.u;
    }
}

// ---------------------------------------------------------------------------
// Prop: 256 blocks x 512 threads (8 waves -> 2 waves/SIMD at 1 block/CU).
// Rationale: R11's branchless ring cut VGPR to 72, so the 512-thread shape
// finally fits any allocator cap (live set ~92) -- no spill risk, and we get
// 2-wave TLP without doubling L2 traffic (unlike a 512-block NB=4 split).
// *** Lore (R4-R10): min-waves launch-bounds args clamp VGPR to 128 and this
// *** family spilled whenever live set >128; keep loads BRANCHLESS (R11) so
// *** the live set stays small and loads hoist to distance-3.
// bid&7 -> XCD; br = (bid&7)>>2 (one branch's 2 MiB per XCD L2).
// Wave owns 32 h (ho=wave). Chunk = 2 rows = 64 uint4; lane loads 1 uint4
// per array. Lane subset (lane>>5) covers even/odd rows; subsets combine
// via shfl_xor(32) before the LDS reduce (identical to R11's 8-slot reduce).
// Math: v_pk_fma_f16 + v_pk_max_f16 (1 VALU instr / element).
// ---------------------------------------------------------------------------
__global__ __launch_bounds__(512) void prop_h_k(const _Float16* __restrict__ wsh,
                                                const float* __restrict__ val,
                                                float* __restrict__ out) {
    const int bid  = blockIdx.x;
    const int x    = bid & 7;             // XCD hint
    const int br   = x >> 2;              // branch -> XCD half
    const int bg   = (bid >> 3) * 4 + (x & 3);   // 0..127
    const int t    = threadIdx.x;
    const int wave = t >> 6;              // 0..7 = ho
    const int lane = t & 63;

    const int arrM = br ? 2 : 0;
    const int arrB = br ? 3 : 1;
    // uint4 units: HOBLK/8 = 8192 uint4 per (arr,ho); chunk = 64 uint4
    const uint4* __restrict__ mp = (const uint4*)wsh + (size_t)(arrM * 8 + wave) * (HOBLK / 8) + lane;
    const uint4* __restrict__ bp = (const uint4*)wsh + (size_t)(arrB * 8 + wave) * (HOBLK / 8) + lane;

    h2 q2[NB];
#pragma unroll
    for (int nb = 0; nb < NB; ++nb) {
        const _Float16 qh = (_Float16)val[bg * NB + nb];   // block-uniform
        q2[nb].x = qh; q2[nb].y = qh;
    }

    __shared__ h2 part[8][NB][128];   // 32 KB: [wave][nb][w/2]
    __shared__ float qs[NB];

    union H8 { uint4 u; h2 h[4]; };

    // 4-slot ring, 8 uint4 = 32 VGPRs of prefetch state
    uint4 bm[4], bb[4];
#pragma unroll
    for (int s = 0; s < 3; ++s) {          // prologue: chunks 0..2
        bm[s] = mp[0]; bb[s] = bp[0];
        mp += 64; bp += 64;
    }

    union { unsigned short us; _Float16 f; } ninf; ninf.us = 0xFC00;  // -inf
    h2 NEGINF; NEGINF.x = ninf.f; NEGINF.y = ninf.f;

    for (int d = 0; d < NDEPTH; ++d) {
        h2 acc[NB][4];
#pragma unroll
        for (int nb = 0; nb < NB; ++nb)
#pragma unroll
            for (int k = 0; k < 4; ++k) acc[nb][k] = NEGINF;

#pragma unroll
        for (int c = 0; c < 16; ++c) {     // 16 chunks of 2 rows per depth
            const int slot = c & 3;        // compile-time per unrolled iter
            const int ps   = (c + 3) & 3;
            // BRANCHLESS prefetch (over-reads <=3 KB into ws pad; unused)
            bm[ps] = mp[0]; bb[ps] = bp[0];
            mp += 64; bp += 64;

            H8 m0, b0;
            m0.u = bm[slot]; b0.u = bb[slot];
#pragma unroll
            for (int nb = 0; nb < NB; ++nb) {
                const h2 qq = q2[nb];
#pragma unroll
                for (int k = 0; k < 4; ++k) {
                    acc[nb][k] = __builtin_elementwise_max(
                        acc[nb][k], __builtin_elementwise_fma(qq, m0.h[k], b0.h[k]));
                }
            }
        }

        // combine the two 16-row lane subsets (lane ^ 32 holds same w slice)
#pragma unroll
        for (int nb = 0; nb < NB; ++nb)
#pragma unroll
            for (int k = 0; k < 4; ++k) {
                const int av = __builtin_bit_cast(int, acc[nb][k]);
                const int ov = __shfl_xor(av, 32, 64);
                const h2 other = __builtin_bit_cast(h2, ov);
                acc[nb][k] = __builtin_elementwise_max(acc[nb][k], other);
            }

        // stage partials: wave slot, lane<32 owns w = (lane&31)*8..+7
        if (lane < 32) {
            const int j32 = lane & 31;
#pragma unroll
            for (int nb = 0; nb < NB; ++nb) {
                H8 st;
                st.h[0] = acc[nb][0]; st.h[1] = acc[nb][1];
                st.h[2] = acc[nb][2]; st.h[3] = acc[nb][3];
                *(uint4*)&part[wave][nb][j32 * 4] = st.u;
            }
        }
        __syncthreads();

        // reduce (threads 0..255): nb = t>>5 (0..7), j = t&31 (w j*8..+7)
        if (t < 256) {
            const int nb = t >> 5;
            const int j  = t & 31;
            H8 v; v.u = *(const uint4*)&part[0][nb][j * 4];
#pragma unroll
            for (int s2 = 1; s2 < 8; ++s2) {
                H8 w2; w2.u = *(const uint4*)&part[s2][nb][j * 4];
#pragma unroll
                for (int k = 0; k < 4; ++k)
                    v.h[k] = __builtin_elementwise_max(v.h[k], w2.h[k]);
            }
            h2 mn = __builtin_elementwise_min(
                        __builtin_elementwise_min(v.h[0], v.h[1]),
                        __builtin_elementwise_min(v.h[2], v.h[3]));
            float r = fminf((float)mn.x, (float)mn.y);
#pragma unroll
            for (int off = 16; off > 0; off >>= 1)
                r = fminf(r, __shfl_xor(r, off, 32));   // min within 32-lane group
            if (j == 0) qs[nb] = r;
        }
        __syncthreads();
#pragma unroll
        for (int nb = 0; nb < NB; ++nb) {
            const _Float16 qh = (_Float16)qs[nb];
            q2[nb].x = qh; q2[nb].y = qh;
        }
        // part[] rewritten only after this barrier next depth -> safe
    }

    if (t < NB) out[br * NBATCH + bg * NB + t] = qs[t];
}

// ---------------------------------------------------------------------------
extern "C" void kernel_launch(void* const* d_in, const int* in_sizes, int n_in,
                              void* d_out, int out_size, void* d_ws, size_t ws_size,
                              hipStream_t stream) {
    const float* val = (const float*)d_in[0];
    const float* M1  = (const float*)d_in[1];
    const float* B1  = (const float*)d_in[2];
    const float* M2  = (const float*)d_in[3];
    const float* B2  = (const float*)d_in[4];
    float*    out = (float*)d_out;
    _Float16* wsh = (_Float16*)d_ws;   // 4 MiB + over-read pad (ws >= 8 MiB, R2)

    transpose_half_k<<<dim3(512), dim3(256), 0, stream>>>(M1, B1, M2, B2, wsh);
    prop_h_k<<<dim3(256), dim3(512), 0, stream>>>(wsh, val, out);
}